// Round 7
// baseline (169.434 us; speedup 1.0000x reference)
//
#include <hip/hip_runtime.h>
#include <hip/hip_bf16.h>

// CorrelatorK3: B=8, N=256, D=64, F=64
// Stage 1 (unchanged from R6): A/Bm bf16 workspace, f-permuted kk.
// Stage 2 (R7 rewrite): one block = full 256x256 C_b x 8-i chunk.
//   grid 256 = 8b x 32kc, 1024 thr (16 waves, 4x4), wave-tile 64x64.
//   A,Bm each read EXACTLY once (262MB demand vs 524MB in R6's 128x128 tiles).

typedef __bf16 bf16x8 __attribute__((ext_vector_type(8)));
typedef float  f32x4  __attribute__((ext_vector_type(4)));
typedef int    i32x4  __attribute__((ext_vector_type(4)));
typedef unsigned short u16;
typedef u16    u16x8  __attribute__((ext_vector_type(8)));

static __device__ __forceinline__ __bf16 f2bf(float x) {
  union { __hip_bfloat16 h; __bf16 b; } u;
  u.h = __float2bfloat16(x);
  return u.b;
}
static __device__ __forceinline__ u16 f2bfu(float x) {
  union { __hip_bfloat16 h; u16 s; } u;
  u.h = __float2bfloat16(x);
  return u.s;
}
static __device__ __forceinline__ float bfu2f(u16 s) {
  union { unsigned int u; float f; } v;
  v.u = ((unsigned int)s) << 16;
  return v.f;
}
static __device__ __forceinline__ void gload16_nt(const float* gsrc, float* ldst) {
  __builtin_amdgcn_global_load_lds(
      (const __attribute__((address_space(1))) void*)gsrc,
      (__attribute__((address_space(3))) void*)ldst, 16, 0, 2);
}
static __device__ __forceinline__ void gload16u(const u16* gsrc, u16* ldst) {
  __builtin_amdgcn_global_load_lds(
      (const __attribute__((address_space(1))) void*)gsrc,
      (__attribute__((address_space(3))) void*)ldst, 16, 0, 0);
}

// ---------------------------------------------------------------- stage 1 ---
// (byte-identical to R6) Grid MUST be 2048 x 256thr.
__global__ __launch_bounds__(256, 3) void k_phase1(
    const float* __restrict__ rbf0, const float* __restrict__ rbfd,
    const float* __restrict__ Q0w, const float* __restrict__ Q0b,
    const float* __restrict__ Qw,  const float* __restrict__ Qb,
    const float* __restrict__ R0w, const float* __restrict__ R0b,
    const float* __restrict__ Rw,  const float* __restrict__ Rb,
    u16* __restrict__ Aout, u16* __restrict__ Bout)
{
  __shared__ __align__(16) float lds[3][2][2048];

  const int tid  = threadIdx.x;
  const int lane = tid & 63;
  const int wave = tid >> 6;
  const int fr   = lane & 15;
  const int kg   = lane >> 4;
  const int role = wave >> 1;
  const int s    = wave & 1;

  const float* W0 = role ? R0w : Q0w;
  const float* W1 = role ? Rw  : Qw;
  const float* B0 = role ? R0b : Q0b;
  const float* B1 = role ? Rb  : Qb;
  u16* __restrict__ Out = role ? Bout : Aout;

  bf16x8 wf0[2][4], wf1[2][4];
#pragma unroll
  for (int kt = 0; kt < 2; ++kt)
#pragma unroll
    for (int ft = 0; ft < 4; ++ft) {
      const float* p0 = W0 + (ft * 16 + fr) * 64 + kt * 32 + kg * 8;
      const float* p1 = W1 + (ft * 16 + fr) * 64 + kt * 32 + kg * 8;
      f32x4 a = *(const f32x4*)p0, b = *(const f32x4*)(p0 + 4);
      f32x4 c = *(const f32x4*)p1, d = *(const f32x4*)(p1 + 4);
      bf16x8 w0v, w1v;
#pragma unroll
      for (int j = 0; j < 4; ++j) {
        w0v[j] = f2bf(a[j]); w0v[j + 4] = f2bf(b[j]);
        w1v[j] = f2bf(c[j]); w1v[j + 4] = f2bf(d[j]);
      }
      wf0[kt][ft] = w0v; wf1[kt][ft] = w1v;
    }

  u16x8 pb0[2], pb1[2];
#pragma unroll
  for (int ft = 0; ft < 4; ++ft)
#pragma unroll
    for (int r = 0; r < 4; ++r) {
      int idx = ft * 4 + r;
      pb0[idx >> 3][idx & 7] = f2bfu(B0[ft * 16 + kg * 4 + r]);
      pb1[idx >> 3][idx & 7] = f2bfu(B1[ft * 16 + kg * 4 + r]);
    }

  const int g0 = tid, g1 = 256 + tid;
  const int c0 = ((g0 >> 4) << 4) | ((g0 & 15) ^ ((g0 >> 4) & 15));
  const int c1 = ((g1 >> 4) << 4) | ((g1 & 15) ^ ((g1 >> 4) & 15));
  const int f0 = c0 * 4, f1 = c1 * 4;
  const int d0 = wave * 256, d1 = (wave + 4) * 256;

  const int bt0 = blockIdx.x;

#define S1_ISSUE(IT, SET)                                              \
  {                                                                    \
    const float* b0_ = rbf0 + (size_t)(bt0 + (IT) * 2048) * 2048;      \
    const float* b1_ = rbfd + (size_t)(bt0 + (IT) * 2048) * 2048;      \
    gload16_nt(b0_ + f0, &lds[SET][0][d0]);                            \
    gload16_nt(b0_ + f1, &lds[SET][0][d1]);                            \
    gload16_nt(b1_ + f0, &lds[SET][1][d0]);                            \
    gload16_nt(b1_ + f1, &lds[SET][1][d1]);                            \
  }

#define S1_COMPUTE(IT, SET)                                            \
  {                                                                    \
    const int row = s * 16 + fr;                                       \
    f32x4 ra[4], rb[4];                                                \
    _Pragma("unroll")                                                  \
    for (int kt = 0; kt < 2; ++kt)                                     \
      _Pragma("unroll")                                                \
      for (int h = 0; h < 2; ++h) {                                    \
        int c = kt * 8 + kg * 2 + h;                                   \
        int chunk = (row << 4) | (c ^ fr);                             \
        ra[kt * 2 + h] = *(const f32x4*)&lds[SET][0][chunk * 4];       \
        rb[kt * 2 + h] = *(const f32x4*)&lds[SET][1][chunk * 4];       \
      }                                                                \
    bf16x8 x0f[2], xdf[2];                                             \
    _Pragma("unroll")                                                  \
    for (int kt = 0; kt < 2; ++kt)                                     \
      _Pragma("unroll")                                                \
      for (int j = 0; j < 4; ++j) {                                    \
        x0f[kt][j]     = f2bf(ra[kt * 2][j]);                          \
        x0f[kt][j + 4] = f2bf(ra[kt * 2 + 1][j]);                      \
        xdf[kt][j]     = f2bf(rb[kt * 2][j]);                          \
        xdf[kt][j + 4] = f2bf(rb[kt * 2 + 1][j]);                      \
      }                                                                \
    f32x4 acc0[4], acc1[4];                                            \
    _Pragma("unroll")                                                  \
    for (int ft = 0; ft < 4; ++ft)                                     \
      _Pragma("unroll")                                                \
      for (int r = 0; r < 4; ++r) {                                    \
        int idx = ft * 4 + r;                                          \
        acc0[ft][r] = bfu2f(pb0[idx >> 3][idx & 7]);                   \
        acc1[ft][r] = bfu2f(pb1[idx >> 3][idx & 7]);                   \
      }                                                                \
    _Pragma("unroll")                                                  \
    for (int kt = 0; kt < 2; ++kt)                                     \
      _Pragma("unroll")                                                \
      for (int ft = 0; ft < 4; ++ft) {                                 \
        acc0[ft] = __builtin_amdgcn_mfma_f32_16x16x32_bf16(            \
            wf0[kt][ft], x0f[kt], acc0[ft], 0, 0, 0);                  \
        acc1[ft] = __builtin_amdgcn_mfma_f32_16x16x32_bf16(            \
            wf1[kt][ft], xdf[kt], acc1[ft], 0, 0, 0);                  \
      }                                                                \
    u16x8 o0, o1;                                                      \
    _Pragma("unroll")                                                  \
    for (int ft = 0; ft < 4; ++ft)                                     \
      _Pragma("unroll")                                                \
      for (int r = 0; r < 4; ++r) {                                    \
        int idx = ft * 4 + r;                                          \
        float v = acc0[ft][r] * acc1[ft][r];                           \
        if (idx < 8) o0[idx & 7] = f2bfu(v); else o1[idx & 7] = f2bfu(v); \
      }                                                                \
    u16* dst = Out + ((size_t)((bt0 + (IT) * 2048) * 32 + s * 16 + fr)) * 64 + kg * 16; \
    *(u16x8*)dst       = o0;                                           \
    *(u16x8*)(dst + 8) = o1;                                           \
  }

#define S1_ITER(IT, NWAIT, DO_ISSUE)                                   \
  {                                                                    \
    if (DO_ISSUE) S1_ISSUE((IT) + 2, ((IT) + 2) % 3);                  \
    asm volatile("s_waitcnt vmcnt(" #NWAIT ")" ::: "memory");          \
    __builtin_amdgcn_s_barrier();                                      \
    __builtin_amdgcn_sched_barrier(0);                                 \
    S1_COMPUTE(IT, (IT) % 3);                                          \
    asm volatile("s_waitcnt lgkmcnt(0)" ::: "memory");                 \
    __builtin_amdgcn_s_barrier();                                      \
    __builtin_amdgcn_sched_barrier(0);                                 \
  }

  S1_ISSUE(0, 0);
  S1_ISSUE(1, 1);

  S1_ITER(0,  8, 1);
  S1_ITER(1, 10, 1);
  S1_ITER(2, 12, 1);
  S1_ITER(3, 12, 1);
  S1_ITER(4, 12, 1);
  S1_ITER(5, 12, 1);
  S1_ITER(6,  8, 0);
  S1_ITER(7,  4, 0);

#undef S1_ITER
#undef S1_COMPUTE
#undef S1_ISSUE
}

// ---------------------------------------------------------------- stage 2 ---
// Grid: 256 blocks = 8 b * 32 kc (8 i's each). Block = 1024 thr, 16 waves 4x4,
// wave-tile 64x64 (acc 64 AGPR). Per i-step: A_i[256x64] + B_i[256x64] bf16
// staged via global_load_lds (pre-swizzled source ch^=(row&7); linear dest;
// swizzled read -> 2-way bank alias, free). Double-buffered 128KB LDS,
// counted vmcnt(4) (4 gl_lds/wave/iter). A,Bm each read exactly once.
__global__ __launch_bounds__(1024, 4) void k_phase2(
    const u16* __restrict__ A, const u16* __restrict__ Bm,
    float* __restrict__ C)
{
  __shared__ __align__(16) u16 As[2][16384];
  __shared__ __align__(16) u16 Bs[2][16384];

  const int tid  = threadIdx.x;
  const int lane = tid & 63;
  const int wave = tid >> 6;      // 0..15
  const int fr   = lane & 15;
  const int kg   = lane >> 4;
  const int wr   = wave >> 2;     // 0..3 (n-quadrant)
  const int wc   = wave & 3;      // 0..3 (j-quadrant)

  const int bid = blockIdx.x;     // 256 = 8b * 32kc
  const int kc  = bid & 31;
  const int b   = bid >> 5;
  const int i0  = kc * 8;

  const u16* Ab = A  + (size_t)b * 4194304;
  const u16* Bb = Bm + (size_t)b * 4194304;

  // staging: 2048 16B-chunks per tensor; pass p, wave w, lane l -> g = p*1024+w*64+l
  // row = g>>3, ch = g&7; source chunk pre-swizzled ch^(row&7); dest linear g.
  const int gA0 = wave * 64 + lane, gA1 = 1024 + gA0;
  const int r0 = gA0 >> 3, ch0 = gA0 & 7, cs0 = ch0 ^ (r0 & 7);
  const int r1 = gA1 >> 3, ch1 = gA1 & 7, cs1 = ch1 ^ (r1 & 7);
  const int rowA0 = r0 * 16384 + cs0 * 8;   // + i*64
  const int rowA1 = r1 * 16384 + cs1 * 8;
  const int rowB0 = r0 * 64 + cs0 * 8;      // + i*16384
  const int rowB1 = r1 * 64 + cs1 * 8;
  const int dst0 = (wave * 64) * 8;         // u16 offset, lane*16B auto
  const int dst1 = (1024 + wave * 64) * 8;

  f32x4 acc[4][4];
#pragma unroll
  for (int mt = 0; mt < 4; ++mt)
#pragma unroll
    for (int nn = 0; nn < 4; ++nn) {
      acc[mt][nn][0] = 0.f; acc[mt][nn][1] = 0.f;
      acc[mt][nn][2] = 0.f; acc[mt][nn][3] = 0.f;
    }

#define S2_ISSUE(I, BUF)                                               \
  {                                                                    \
    gload16u(Ab + rowA0 + (I) * 64, &As[BUF][dst0]);                   \
    gload16u(Ab + rowA1 + (I) * 64, &As[BUF][dst1]);                   \
    gload16u(Bb + rowB0 + (size_t)(I) * 16384, &Bs[BUF][dst0]);        \
    gload16u(Bb + rowB1 + (size_t)(I) * 16384, &Bs[BUF][dst1]);        \
  }

#define S2_COMPUTE(BUF)                                                \
  {                                                                    \
    _Pragma("unroll")                                                  \
    for (int kt = 0; kt < 2; ++kt) {                                   \
      bf16x8 af[4], bfv[4];                                            \
      _Pragma("unroll")                                                \
      for (int mt = 0; mt < 4; ++mt) {                                 \
        int row = wr * 64 + mt * 16 + fr;                              \
        int c = kt * 4 + kg;                                           \
        af[mt] = *(const bf16x8*)&As[BUF][row * 64 + ((c ^ (row & 7)) * 8)]; \
      }                                                                \
      _Pragma("unroll")                                                \
      for (int nn = 0; nn < 4; ++nn) {                                 \
        int row = wc * 64 + nn * 16 + fr;                              \
        int c = kt * 4 + kg;                                           \
        bfv[nn] = *(const bf16x8*)&Bs[BUF][row * 64 + ((c ^ (row & 7)) * 8)]; \
      }                                                                \
      _Pragma("unroll")                                                \
      for (int mt = 0; mt < 4; ++mt)                                   \
        _Pragma("unroll")                                              \
        for (int nn = 0; nn < 4; ++nn)                                 \
          acc[mt][nn] = __builtin_amdgcn_mfma_f32_16x16x32_bf16(       \
              af[mt], bfv[nn], acc[mt][nn], 0, 0, 0);                  \
    }                                                                  \
  }

#define S2_ITER(IT, NWAIT, DO_ISSUE)                                   \
  {                                                                    \
    if (DO_ISSUE) S2_ISSUE(i0 + (IT) + 1, ((IT) + 1) & 1);             \
    asm volatile("s_waitcnt vmcnt(" #NWAIT ")" ::: "memory");          \
    __builtin_amdgcn_s_barrier();                                      \
    __builtin_amdgcn_sched_barrier(0);                                 \
    S2_COMPUTE((IT) & 1);                                              \
    asm volatile("s_waitcnt lgkmcnt(0)" ::: "memory");                 \
    __builtin_amdgcn_s_barrier();                                      \
    __builtin_amdgcn_sched_barrier(0);                                 \
  }

  S2_ISSUE(i0, 0);

  S2_ITER(0, 4, 1);
  S2_ITER(1, 4, 1);
  S2_ITER(2, 4, 1);
  S2_ITER(3, 4, 1);
  S2_ITER(4, 4, 1);
  S2_ITER(5, 4, 1);
  S2_ITER(6, 4, 1);
  S2_ITER(7, 0, 0);

#undef S2_ITER
#undef S2_COMPUTE
#undef S2_ISSUE

  float* Cb = C + ((size_t)b << 16);
#pragma unroll
  for (int mt = 0; mt < 4; ++mt)
#pragma unroll
    for (int nn = 0; nn < 4; ++nn)
#pragma unroll
      for (int r = 0; r < 4; ++r) {
        int n = wr * 64 + mt * 16 + kg * 4 + r;
        int j = wc * 64 + nn * 16 + fr;
        atomicAdd(&Cb[n * 256 + j], acc[mt][nn][r] * 0.02f);
      }
}

// ------------------------------------------------------------------ launch --
extern "C" void kernel_launch(void* const* d_in, const int* in_sizes, int n_in,
                              void* d_out, int out_size, void* d_ws, size_t ws_size,
                              hipStream_t stream)
{
  const float* rbf0 = (const float*)d_in[0];
  const float* rbfd = (const float*)d_in[1];
  const float* Q0w  = (const float*)d_in[2];
  const float* Q0b  = (const float*)d_in[3];
  const float* Qw   = (const float*)d_in[4];
  const float* Qb   = (const float*)d_in[5];
  const float* R0w  = (const float*)d_in[6];
  const float* R0b  = (const float*)d_in[7];
  const float* Rw   = (const float*)d_in[8];
  const float* Rb   = (const float*)d_in[9];
  float* out = (float*)d_out;

  u16* Abuf = (u16*)d_ws;
  u16* Bbuf = Abuf + (size_t)33554432;

  hipMemsetAsync(d_out, 0, (size_t)out_size * sizeof(float), stream);
  hipLaunchKernelGGL(k_phase1, dim3(2048), dim3(256), 0, stream,
                     rbf0, rbfd, Q0w, Q0b, Qw, Qb, R0w, R0b, Rw, Rb, Abuf, Bbuf);
  hipLaunchKernelGGL(k_phase2, dim3(256), dim3(1024), 0, stream, Abuf, Bbuf, out);
}

// Round 8
// 144.810 us; speedup vs baseline: 1.1700x; 1.1700x over previous
//
#include <hip/hip_runtime.h>
#include <hip/hip_bf16.h>

// CorrelatorK3: B=8, N=256, D=64, F=64
// Stage 1 (byte-identical to R6): NT global_load_lds staging, 3-set LDS,
//   depth-2 counted-vmcnt pipeline. A/Bm bf16 workspace, f-permuted kk.
// Stage 2 (R8): R6's 128x128-tile kernel + XCD co-residency swizzle:
//   the 4 quads (2nt x 2jt) of each (b,kc) group are placed at blockIdx
//   values congruent mod 8 -> same XCD (bid%8=XCD, m09) -> second read of
//   each A_i/B_i tile hits that XCD's L2, halving beyond-L2 demand.

typedef __bf16 bf16x8 __attribute__((ext_vector_type(8)));
typedef float  f32x4  __attribute__((ext_vector_type(4)));
typedef int    i32x4  __attribute__((ext_vector_type(4)));
typedef unsigned short u16;
typedef u16    u16x8  __attribute__((ext_vector_type(8)));

static __device__ __forceinline__ __bf16 f2bf(float x) {
  union { __hip_bfloat16 h; __bf16 b; } u;
  u.h = __float2bfloat16(x);
  return u.b;
}
static __device__ __forceinline__ u16 f2bfu(float x) {
  union { __hip_bfloat16 h; u16 s; } u;
  u.h = __float2bfloat16(x);
  return u.s;
}
static __device__ __forceinline__ float bfu2f(u16 s) {
  union { unsigned int u; float f; } v;
  v.u = ((unsigned int)s) << 16;
  return v.f;
}
static __device__ __forceinline__ void gload16_nt(const float* gsrc, float* ldst) {
  __builtin_amdgcn_global_load_lds(
      (const __attribute__((address_space(1))) void*)gsrc,
      (__attribute__((address_space(3))) void*)ldst, 16, 0, 2);
}

// ---------------------------------------------------------------- stage 1 ---
// (byte-identical to R6) Grid MUST be 2048 x 256thr.
__global__ __launch_bounds__(256, 3) void k_phase1(
    const float* __restrict__ rbf0, const float* __restrict__ rbfd,
    const float* __restrict__ Q0w, const float* __restrict__ Q0b,
    const float* __restrict__ Qw,  const float* __restrict__ Qb,
    const float* __restrict__ R0w, const float* __restrict__ R0b,
    const float* __restrict__ Rw,  const float* __restrict__ Rb,
    u16* __restrict__ Aout, u16* __restrict__ Bout)
{
  __shared__ __align__(16) float lds[3][2][2048];

  const int tid  = threadIdx.x;
  const int lane = tid & 63;
  const int wave = tid >> 6;
  const int fr   = lane & 15;
  const int kg   = lane >> 4;
  const int role = wave >> 1;
  const int s    = wave & 1;

  const float* W0 = role ? R0w : Q0w;
  const float* W1 = role ? Rw  : Qw;
  const float* B0 = role ? R0b : Q0b;
  const float* B1 = role ? Rb  : Qb;
  u16* __restrict__ Out = role ? Bout : Aout;

  bf16x8 wf0[2][4], wf1[2][4];
#pragma unroll
  for (int kt = 0; kt < 2; ++kt)
#pragma unroll
    for (int ft = 0; ft < 4; ++ft) {
      const float* p0 = W0 + (ft * 16 + fr) * 64 + kt * 32 + kg * 8;
      const float* p1 = W1 + (ft * 16 + fr) * 64 + kt * 32 + kg * 8;
      f32x4 a = *(const f32x4*)p0, b = *(const f32x4*)(p0 + 4);
      f32x4 c = *(const f32x4*)p1, d = *(const f32x4*)(p1 + 4);
      bf16x8 w0v, w1v;
#pragma unroll
      for (int j = 0; j < 4; ++j) {
        w0v[j] = f2bf(a[j]); w0v[j + 4] = f2bf(b[j]);
        w1v[j] = f2bf(c[j]); w1v[j + 4] = f2bf(d[j]);
      }
      wf0[kt][ft] = w0v; wf1[kt][ft] = w1v;
    }

  u16x8 pb0[2], pb1[2];
#pragma unroll
  for (int ft = 0; ft < 4; ++ft)
#pragma unroll
    for (int r = 0; r < 4; ++r) {
      int idx = ft * 4 + r;
      pb0[idx >> 3][idx & 7] = f2bfu(B0[ft * 16 + kg * 4 + r]);
      pb1[idx >> 3][idx & 7] = f2bfu(B1[ft * 16 + kg * 4 + r]);
    }

  const int g0 = tid, g1 = 256 + tid;
  const int c0 = ((g0 >> 4) << 4) | ((g0 & 15) ^ ((g0 >> 4) & 15));
  const int c1 = ((g1 >> 4) << 4) | ((g1 & 15) ^ ((g1 >> 4) & 15));
  const int f0 = c0 * 4, f1 = c1 * 4;
  const int d0 = wave * 256, d1 = (wave + 4) * 256;

  const int bt0 = blockIdx.x;

#define S1_ISSUE(IT, SET)                                              \
  {                                                                    \
    const float* b0_ = rbf0 + (size_t)(bt0 + (IT) * 2048) * 2048;      \
    const float* b1_ = rbfd + (size_t)(bt0 + (IT) * 2048) * 2048;      \
    gload16_nt(b0_ + f0, &lds[SET][0][d0]);                            \
    gload16_nt(b0_ + f1, &lds[SET][0][d1]);                            \
    gload16_nt(b1_ + f0, &lds[SET][1][d0]);                            \
    gload16_nt(b1_ + f1, &lds[SET][1][d1]);                            \
  }

#define S1_COMPUTE(IT, SET)                                            \
  {                                                                    \
    const int row = s * 16 + fr;                                       \
    f32x4 ra[4], rb[4];                                                \
    _Pragma("unroll")                                                  \
    for (int kt = 0; kt < 2; ++kt)                                     \
      _Pragma("unroll")                                                \
      for (int h = 0; h < 2; ++h) {                                    \
        int c = kt * 8 + kg * 2 + h;                                   \
        int chunk = (row << 4) | (c ^ fr);                             \
        ra[kt * 2 + h] = *(const f32x4*)&lds[SET][0][chunk * 4];       \
        rb[kt * 2 + h] = *(const f32x4*)&lds[SET][1][chunk * 4];       \
      }                                                                \
    bf16x8 x0f[2], xdf[2];                                             \
    _Pragma("unroll")                                                  \
    for (int kt = 0; kt < 2; ++kt)                                     \
      _Pragma("unroll")                                                \
      for (int j = 0; j < 4; ++j) {                                    \
        x0f[kt][j]     = f2bf(ra[kt * 2][j]);                          \
        x0f[kt][j + 4] = f2bf(ra[kt * 2 + 1][j]);                      \
        xdf[kt][j]     = f2bf(rb[kt * 2][j]);                          \
        xdf[kt][j + 4] = f2bf(rb[kt * 2 + 1][j]);                      \
      }                                                                \
    f32x4 acc0[4], acc1[4];                                            \
    _Pragma("unroll")                                                  \
    for (int ft = 0; ft < 4; ++ft)                                     \
      _Pragma("unroll")                                                \
      for (int r = 0; r < 4; ++r) {                                    \
        int idx = ft * 4 + r;                                          \
        acc0[ft][r] = bfu2f(pb0[idx >> 3][idx & 7]);                   \
        acc1[ft][r] = bfu2f(pb1[idx >> 3][idx & 7]);                   \
      }                                                                \
    _Pragma("unroll")                                                  \
    for (int kt = 0; kt < 2; ++kt)                                     \
      _Pragma("unroll")                                                \
      for (int ft = 0; ft < 4; ++ft) {                                 \
        acc0[ft] = __builtin_amdgcn_mfma_f32_16x16x32_bf16(            \
            wf0[kt][ft], x0f[kt], acc0[ft], 0, 0, 0);                  \
        acc1[ft] = __builtin_amdgcn_mfma_f32_16x16x32_bf16(            \
            wf1[kt][ft], xdf[kt], acc1[ft], 0, 0, 0);                  \
      }                                                                \
    u16x8 o0, o1;                                                      \
    _Pragma("unroll")                                                  \
    for (int ft = 0; ft < 4; ++ft)                                     \
      _Pragma("unroll")                                                \
      for (int r = 0; r < 4; ++r) {                                    \
        int idx = ft * 4 + r;                                          \
        float v = acc0[ft][r] * acc1[ft][r];                           \
        if (idx < 8) o0[idx & 7] = f2bfu(v); else o1[idx & 7] = f2bfu(v); \
      }                                                                \
    u16* dst = Out + ((size_t)((bt0 + (IT) * 2048) * 32 + s * 16 + fr)) * 64 + kg * 16; \
    *(u16x8*)dst       = o0;                                           \
    *(u16x8*)(dst + 8) = o1;                                           \
  }

#define S1_ITER(IT, NWAIT, DO_ISSUE)                                   \
  {                                                                    \
    if (DO_ISSUE) S1_ISSUE((IT) + 2, ((IT) + 2) % 3);                  \
    asm volatile("s_waitcnt vmcnt(" #NWAIT ")" ::: "memory");          \
    __builtin_amdgcn_s_barrier();                                      \
    __builtin_amdgcn_sched_barrier(0);                                 \
    S1_COMPUTE(IT, (IT) % 3);                                          \
    asm volatile("s_waitcnt lgkmcnt(0)" ::: "memory");                 \
    __builtin_amdgcn_s_barrier();                                      \
    __builtin_amdgcn_sched_barrier(0);                                 \
  }

  S1_ISSUE(0, 0);
  S1_ISSUE(1, 1);

  S1_ITER(0,  8, 1);
  S1_ITER(1, 10, 1);
  S1_ITER(2, 12, 1);
  S1_ITER(3, 12, 1);
  S1_ITER(4, 12, 1);
  S1_ITER(5, 12, 1);
  S1_ITER(6,  8, 0);
  S1_ITER(7,  4, 0);

#undef S1_ITER
#undef S1_COMPUTE
#undef S1_ISSUE
}

// ---------------------------------------------------------------- stage 2 ---
// Grid: 512 blocks = 8 b * 2 nt * 2 jt * 16 kc. Block = 4 waves (2x2),
// tile 128x128. R8 swizzle: quads of a (b,kc) group at bid = xcd + 8*(slot*4+q)
// -> same XCD (bid%8), co-resident -> 2nd read of each A_i/B_i tile = L2 hit.
__global__ __launch_bounds__(256, 2) void k_phase2(
    const u16* __restrict__ A, const u16* __restrict__ Bm,
    float* __restrict__ C)
{
  __shared__ __align__(16) u16 Alds[128 * 64];
  __shared__ __align__(16) u16 Blds[128 * 64];

  const int tid  = threadIdx.x;
  const int lane = tid & 63;
  const int wave = tid >> 6;
  const int fr   = lane & 15;
  const int kg   = lane >> 4;

  // XCD co-residency decode (bijective on [0,512))
  const int bid  = blockIdx.x;
  const int xcd  = bid & 7;
  const int t    = bid >> 3;        // 0..63
  const int q    = t & 3;           // quad within group
  const int slot = t >> 2;          // 0..15
  const int group = slot * 8 + xcd; // 0..127
  const int kc = group & 15;
  const int b  = group >> 4;        // 0..7
  const int nt = q >> 1, jt = q & 1;
  const int n0 = nt * 128, j0 = jt * 128;
  const int wr = wave >> 1, wc = wave & 1;

  const u16* Ab = A  + (size_t)b * 4194304;
  const u16* Bb = Bm + (size_t)b * 4194304;

  f32x4 acc[4][4];
#pragma unroll
  for (int mt = 0; mt < 4; ++mt)
#pragma unroll
    for (int nn = 0; nn < 4; ++nn) {
      acc[mt][nn][0] = 0.f; acc[mt][nn][1] = 0.f;
      acc[mt][nn][2] = 0.f; acc[mt][nn][3] = 0.f;
    }

  for (int ii = 0; ii < 16; ++ii) {
    const int i = kc * 16 + ii;

    i32x4 va[4], vb[4];
#pragma unroll
    for (int rep = 0; rep < 4; ++rep) {
      int c = tid + rep * 256;
      int row = c >> 3, ch = c & 7;
      va[rep] = *(const i32x4*)(Ab + (size_t)(n0 + row) * 16384 + (size_t)i * 64 + ch * 8);
      vb[rep] = *(const i32x4*)(Bb + (size_t)i * 16384 + (size_t)(j0 + row) * 64 + ch * 8);
    }
    __syncthreads();
#pragma unroll
    for (int rep = 0; rep < 4; ++rep) {
      int c = tid + rep * 256;
      int row = c >> 3, ch = c & 7;
      int sw = ch ^ (row & 7);
      *(i32x4*)&Alds[row * 64 + sw * 8] = va[rep];
      *(i32x4*)&Blds[row * 64 + sw * 8] = vb[rep];
    }
    __syncthreads();

#pragma unroll
    for (int ks = 0; ks < 2; ++ks) {
      bf16x8 af[4], bfv[4];
#pragma unroll
      for (int mt = 0; mt < 4; ++mt) {
        int row = wr * 64 + mt * 16 + fr;
        int sw = (ks * 4 + kg) ^ (row & 7);
        af[mt] = *(const bf16x8*)&Alds[row * 64 + sw * 8];
      }
#pragma unroll
      for (int nn = 0; nn < 4; ++nn) {
        int row = wc * 64 + nn * 16 + fr;
        int sw = (ks * 4 + kg) ^ (row & 7);
        bfv[nn] = *(const bf16x8*)&Blds[row * 64 + sw * 8];
      }
#pragma unroll
      for (int mt = 0; mt < 4; ++mt)
#pragma unroll
        for (int nn = 0; nn < 4; ++nn)
          acc[mt][nn] = __builtin_amdgcn_mfma_f32_16x16x32_bf16(af[mt], bfv[nn], acc[mt][nn], 0, 0, 0);
    }
  }

  float* Cb = C + ((size_t)b << 16);
#pragma unroll
  for (int mt = 0; mt < 4; ++mt)
#pragma unroll
    for (int nn = 0; nn < 4; ++nn)
#pragma unroll
      for (int r = 0; r < 4; ++r) {
        int n = n0 + wr * 64 + mt * 16 + kg * 4 + r;
        int j = j0 + wc * 64 + nn * 16 + fr;
        atomicAdd(&Cb[n * 256 + j], acc[mt][nn][r] * 0.02f);
      }
}

// ------------------------------------------------------------------ launch --
extern "C" void kernel_launch(void* const* d_in, const int* in_sizes, int n_in,
                              void* d_out, int out_size, void* d_ws, size_t ws_size,
                              hipStream_t stream)
{
  const float* rbf0 = (const float*)d_in[0];
  const float* rbfd = (const float*)d_in[1];
  const float* Q0w  = (const float*)d_in[2];
  const float* Q0b  = (const float*)d_in[3];
  const float* Qw   = (const float*)d_in[4];
  const float* Qb   = (const float*)d_in[5];
  const float* R0w  = (const float*)d_in[6];
  const float* R0b  = (const float*)d_in[7];
  const float* Rw   = (const float*)d_in[8];
  const float* Rb   = (const float*)d_in[9];
  float* out = (float*)d_out;

  u16* Abuf = (u16*)d_ws;
  u16* Bbuf = Abuf + (size_t)33554432;

  hipMemsetAsync(d_out, 0, (size_t)out_size * sizeof(float), stream);
  hipLaunchKernelGGL(k_phase1, dim3(2048), dim3(256), 0, stream,
                     rbf0, rbfd, Q0w, Q0b, Qw, Qb, R0w, R0b, Rw, Rb, Abuf, Bbuf);
  hipLaunchKernelGGL(k_phase2, dim3(512), dim3(256), 0, stream, Abuf, Bbuf, out);
}